// Round 5
// baseline (239.374 us; speedup 1.0000x reference)
//
#include <hip/hip_runtime.h>

#define CH 64
#define HW 3136
#define MTOT 401408   // 128*3136
#define TPX 128       // px per tile
#define NBLK 784      // 784 blocks x 4 tiles x 128 px = 401408
#define TPB 4

typedef __attribute__((ext_vector_type(8))) short short8;   // 8 bf16 (4 VGPRs)
typedef __attribute__((ext_vector_type(4))) float f32x4;
typedef __attribute__((ext_vector_type(4))) unsigned int u32x4;

// hi/lo bf16 split of 8 fp32 values (truncation + exact residual; proven r1-r4)
__device__ __forceinline__ void split8(const float4 a, const float4 b,
                                       short8& hi, short8& lo, float& ssum){
  const float f[8] = {a.x,a.y,a.z,a.w, b.x,b.y,b.z,b.w};
  u32x4 hp, lp;
#pragma unroll
  for (int j=0;j<4;++j){
    const unsigned int b0 = __float_as_uint(f[2*j]);
    const unsigned int b1 = __float_as_uint(f[2*j+1]);
    hp[j] = (b0 >> 16) | (b1 & 0xFFFF0000u);
    const float h0 = __uint_as_float(b0 & 0xFFFF0000u);
    const float h1 = __uint_as_float(b1 & 0xFFFF0000u);
    const unsigned int l0 = __float_as_uint(f[2*j]   - h0);
    const unsigned int l1 = __float_as_uint(f[2*j+1] - h1);
    lp[j] = (l0 >> 16) | (l1 & 0xFFFF0000u);
  }
  hi = __builtin_bit_cast(short8, hp);
  lo = __builtin_bit_cast(short8, lp);
  ssum += ((f[0]+f[1])+(f[2]+f[3])) + ((f[4]+f[5])+(f[6]+f[7]));
}

// ---------------- K1: covariance via split-bf16 MFMA, counted-vmcnt dbuf ----------------
__global__ __launch_bounds__(256) void k1_cov(const float* __restrict__ X,
                                              float* __restrict__ SR){
  constexpr int RG[10] = {0,1,1,2,2,2,3,3,3,3};
  constexpr int CG[10] = {0,0,1,0,1,2,0,1,2,3};
  __shared__ __align__(16) float buf[2][64*TPX];   // 2 x 32KB double buffer
  __shared__ float chs[64];

  const int t   = threadIdx.x;
  const int wid = __builtin_amdgcn_readfirstlane(t >> 6);
  const int l   = t & 63;
  const int lr  = l & 15;
  const int q   = l >> 4;

  f32x4 acc[10];
#pragma unroll
  for (int bi=0; bi<10; ++bi) acc[bi] = (f32x4){0.f,0.f,0.f,0.f};
  float sums[4] = {0.f,0.f,0.f,0.f};

  auto stage = [&](int tl, float* dst){
    const unsigned mbase = (unsigned)(blockIdx.x*TPB + tl) * TPX;
#pragma unroll
    for (int j=0;j<8;++j){
      const int r  = 16*wid + 2*j + (l>>5);
      const int cb = (l&31) ^ (r&7);
      const unsigned m  = mbase + 4*cb;
      const unsigned b  = m / HW;
      const unsigned hw = m - b*HW;
      const float* src = X + (size_t)b*(CH*HW) + (size_t)r*HW + hw;
      __builtin_amdgcn_global_load_lds(
        (const __attribute__((address_space(1))) unsigned int*)src,
        (__attribute__((address_space(3))) unsigned int*)(dst + (16*wid + 2*j)*TPX),
        16, 0, 0);
    }
  };

  stage(0, buf[0]);
  int pb = 0;
#pragma unroll
  for (int tl=0; tl<TPB; ++tl){
    if (tl+1 < TPB){
      stage(tl+1, buf[pb^1]);
      asm volatile("s_waitcnt vmcnt(8)" ::: "memory");   // only tile tl's 8 loads done
    } else {
      asm volatile("s_waitcnt vmcnt(0)" ::: "memory");
    }
    __builtin_amdgcn_sched_barrier(0);
    asm volatile("s_barrier" ::: "memory");              // raw: no compiler vmcnt drain
    const char* bp = (const char*)buf[pb];
    short8 fh[4], fl[4];
#pragma unroll
    for (int g=0; g<4; ++g){
      const int r   = 16*g + lr;
      const int sw  = r & 7;
      const int cb0 = 8*wid + 2*q;
      const float4 v0 = *(const float4*)(bp + r*512 + 16*((cb0+0)^sw));
      const float4 v1 = *(const float4*)(bp + r*512 + 16*((cb0+1)^sw));
      split8(v0, v1, fh[g], fl[g], sums[g]);
    }
#pragma unroll
    for (int bi=0; bi<10; ++bi){
      acc[bi] = __builtin_amdgcn_mfma_f32_16x16x32_bf16(fh[RG[bi]], fh[CG[bi]], acc[bi], 0,0,0);
      acc[bi] = __builtin_amdgcn_mfma_f32_16x16x32_bf16(fh[RG[bi]], fl[CG[bi]], acc[bi], 0,0,0);
      acc[bi] = __builtin_amdgcn_mfma_f32_16x16x32_bf16(fl[RG[bi]], fh[CG[bi]], acc[bi], 0,0,0);
    }
    asm volatile("s_barrier" ::: "memory");              // all waves done reading buf[pb]
    pb ^= 1;
  }

#pragma unroll
  for (int g=0; g<4; ++g){
    sums[g] += __shfl_xor(sums[g], 16);
    sums[g] += __shfl_xor(sums[g], 32);
  }

  // deterministic cross-wave reduction (red aliases buf[0]; disjoint from last-read buf[1])
  float* red = &buf[0][0];
  for (int w=0; w<4; ++w){
    if (wid == w){
#pragma unroll
      for (int bi=0; bi<10; ++bi){
        const int row0 = RG[bi]*16 + 4*q;
        const int col  = CG[bi]*16 + lr;
#pragma unroll
        for (int r=0; r<4; ++r){
          float* d = &red[(row0+r)*64 + col];
          if (w==0) *d = acc[bi][r]; else *d += acc[bi][r];
        }
      }
      if (l < 16){
#pragma unroll
        for (int g=0; g<4; ++g){
          if (w==0) chs[g*16+l] = sums[g]; else chs[g*16+l] += sums[g];
        }
      }
    }
    __syncthreads();
  }

#pragma unroll
  for (int bi=0; bi<10; ++bi){
    const int r = RG[bi]*16 + (t>>4);
    const int c = CG[bi]*16 + (t&15);
    unsafeAtomicAdd(&SR[r*64+c], red[r*64+c]);
  }
  if (t < 64) unsafeAtomicAdd(&SR[4096+t], chs[t]);
}

// ---------------- K2: whitening matrix (unchanged) ----------------
__device__ __forceinline__ void mm_AtB(const float* a, const float* b, float* out,
                                       float alpha, const float* aff, float beta_){
  const int t = threadIdx.x;
  const int c2 = 2*(t & 31);
  const int r0 = 8*(t >> 5);
  float acc[8][2];
#pragma unroll
  for (int i=0;i<8;++i){ acc[i][0]=0.f; acc[i][1]=0.f; }
  for (int k=0;k<64;++k){
    const float2 bv = *(const float2*)&b[k*64 + c2];
    const float4 a0 = *(const float4*)&a[k*64 + r0];
    const float4 a1 = *(const float4*)&a[k*64 + r0 + 4];
    const float av[8] = {a0.x,a0.y,a0.z,a0.w, a1.x,a1.y,a1.z,a1.w};
#pragma unroll
    for (int i=0;i<8;++i){ acc[i][0] += av[i]*bv.x; acc[i][1] += av[i]*bv.y; }
  }
  float res[8][2];
#pragma unroll
  for (int i=0;i<8;++i){
    float f0 = alpha*acc[i][0], f1 = alpha*acc[i][1];
    if (aff){ f0 += beta_*aff[(r0+i)*64 + c2]; f1 += beta_*aff[(r0+i)*64 + c2 + 1]; }
    res[i][0]=f0; res[i][1]=f1;
  }
  __syncthreads();
#pragma unroll
  for (int i=0;i<8;++i){
    float2 o2; o2.x = res[i][0]; o2.y = res[i][1];
    *(float2*)&out[(r0+i)*64 + c2] = o2;
  }
  __syncthreads();
}

__global__ __launch_bounds__(256) void k2_wm(const float* __restrict__ SR,
                                             const float* __restrict__ beta,
                                             float* __restrict__ WM,
                                             float* __restrict__ OFS){
  __shared__ __align__(16) float bufE[4096];
  __shared__ __align__(16) float bufA[4096];
  __shared__ __align__(16) float bufB[4096];
  __shared__ float meanv[64];
  __shared__ float scal[2];
  const int t = threadIdx.x;
  const float inv_m = 1.f/(float)MTOT;
  if (t < 64) meanv[t] = SR[4096 + t]*inv_m;
  __syncthreads();
  for (int idx=t; idx<4096; idx+=256){
    const int r = idx >> 6, c = idx & 63;
    const int src = ((r >> 4) >= (c >> 4)) ? idx : (c*64 + r);
    const float cov = SR[src]*inv_m - meanv[r]*meanv[c];
    bufE[idx] = (r==c) ? (cov + 1e-5f - 1.f) : 0.9f*cov;
  }
  __syncthreads();
  float n2 = 0.f, tr = 0.f;
  for (int idx=t; idx<4096; idx+=256){
    const float e = bufE[idx];
    n2 += e*e;
    if ((idx >> 6) == (idx & 63)) tr += e;
  }
  bufA[t] = n2; bufB[t] = tr;
  __syncthreads();
  if (t < 64){
    bufA[t] = bufA[t]+bufA[t+64]+bufA[t+128]+bufA[t+192];
    bufB[t] = bufB[t]+bufB[t+64]+bufB[t+128]+bufB[t+192];
  }
  __syncthreads();
  if (t == 0){
    float s1=0.f, s2=0.f;
    for (int i=0;i<64;++i){ s1 += bufA[i]; s2 += bufB[i]; }
    scal[0] = s1; scal[1] = s2;
  }
  __syncthreads();
  const float frob2 = scal[0];
  const float trE   = scal[1];
  float wscale = 1.f;
  const float* wmLds;
  if (frob2 < 0.04f){
    mm_AtB(bufE, bufE, bufA, 1.f, nullptr, 0.f);   // E^2
    mm_AtB(bufA, bufE, bufB, 1.f, nullptr, 0.f);   // E^3
    for (int idx=t; idx<4096; idx+=256){
      const int r = idx >> 6, c = idx & 63;
      bufB[idx] = ((r==c)?1.f:0.f) - 0.5f*bufE[idx] + 0.375f*bufA[idx] - 0.3125f*bufB[idx];
    }
    mm_AtB(bufA, bufA, bufE, 1.f, nullptr, 0.f);   // E^4
    for (int idx=t; idx<4096; idx+=256)
      bufB[idx] += 0.2734375f*bufE[idx];           // 35/128
    wmLds = bufB;
  } else {
    const float rTr = 1.f/(trE + 64.f);
    for (int idx=t; idx<4096; idx+=256){
      const int r = idx >> 6, c = idx & 63;
      bufE[idx] = (bufE[idx] + ((r==c)?1.f:0.f))*rTr;
      bufA[idx] = (r==c)?1.f:0.f;
    }
    __syncthreads();
    for (int it=0; it<10; ++it){
      mm_AtB(bufA, bufE, bufB, 1.f, nullptr, 0.f);
      mm_AtB(bufA, bufB, bufB, 1.f, nullptr, 0.f);
      mm_AtB(bufA, bufB, bufA, -0.5f, bufA, 1.5f);
    }
    wscale = sqrtf(rTr);
    wmLds = bufA;
  }
  __syncthreads();
  for (int idx=t; idx<4096; idx+=256) WM[idx] = wmLds[idx]*wscale;
  if (t < 64){
    float d = 0.f;
    for (int j=0;j<64;++j) d += wmLds[t*64 + j]*meanv[j];
    OFS[t] = beta[t] - d*wscale;
  }
}

// ---------------- K3: apply whitening via MFMA, LDS-staged, counted vmcnt ----------------
// out[c][p] = sum_k WM[c][k]*X[k][p] + OFS[c]
// B-frag needs ch-consecutive per lane -> LDS tile with px-bit4 XOR (ch>>3)&1 swizzle:
// q-parities hit disjoint 16-bank halves -> residual 2-way conflict (free).
__global__ __launch_bounds__(256) void k3_apply(const float* __restrict__ X,
                                                const float* __restrict__ WM,
                                                const float* __restrict__ OFS,
                                                float* __restrict__ out){
  __shared__ __align__(16) float buf[2][64*TPX];   // 2 x 32KB
  const int t   = threadIdx.x;
  const int wid = __builtin_amdgcn_readfirstlane(t >> 6);
  const int l   = t & 63;
  const int lr  = l & 15;     // px-in-16 / A-row / D-col
  const int q   = l >> 4;     // k-octet

  // stationary WM A-fragments (row c = 16cb+lr, k = ks*32+q*8+j), hoisted offsets
  short8 ah[4][2], al[4][2];
  float dummy = 0.f;
#pragma unroll
  for (int cb=0; cb<4; ++cb)
#pragma unroll
    for (int ks=0; ks<2; ++ks){
      const float* wp = WM + (16*cb + lr)*64 + ks*32 + q*8;
      const float4 w0 = *(const float4*)wp;
      const float4 w1 = *(const float4*)(wp + 4);
      split8(w0, w1, ah[cb][ks], al[cb][ks], dummy);
    }
  float ofsv[4][4];
#pragma unroll
  for (int cb=0; cb<4; ++cb)
#pragma unroll
    for (int r=0; r<4; ++r) ofsv[cb][r] = OFS[16*cb + 4*q + r];

  // stage: linear LDS dest; global source px pre-swizzled by (row>>3)&1 on px-bit4
  auto stage = [&](int tl, float* dst){
    const unsigned mbase = (unsigned)(blockIdx.x*TPB + tl) * TPX;
#pragma unroll
    for (int j=0;j<8;++j){
      const int r = 16*wid + 2*j + (l>>5);
      const unsigned pxs = 4*(l&31);
      const unsigned m  = mbase + (pxs ^ (((r>>3)&1u)<<4));
      const unsigned b  = m / HW;
      const unsigned hw = m - b*HW;
      const float* src = X + (size_t)b*(CH*HW) + (size_t)r*HW + hw;
      __builtin_amdgcn_global_load_lds(
        (const __attribute__((address_space(1))) unsigned int*)src,
        (__attribute__((address_space(3))) unsigned int*)(dst + (16*wid + 2*j)*TPX),
        16, 0, 0);
    }
  };

  stage(0, buf[0]);
  int pb = 0;
#pragma unroll
  for (int tl=0; tl<TPB; ++tl){
    if (tl+1 < TPB) stage(tl+1, buf[pb^1]);
    // vmcnt queue (oldest first): [stage(tl) 8][stores(tl-1) 32][stage(tl+1) 8]
    if (tl == 0)          asm volatile("s_waitcnt vmcnt(8)"  ::: "memory");
    else if (tl+1 < TPB)  asm volatile("s_waitcnt vmcnt(40)" ::: "memory");
    else                  asm volatile("s_waitcnt vmcnt(32)" ::: "memory");
    __builtin_amdgcn_sched_barrier(0);
    asm volatile("s_barrier" ::: "memory");

    const float* bp = buf[pb];
    f32x4 acc[4][2];
#pragma unroll
    for (int cb=0; cb<4; ++cb)
#pragma unroll
      for (int pk=0; pk<2; ++pk) acc[cb][pk] = (f32x4){0.f,0.f,0.f,0.f};

#pragma unroll
    for (int ks=0; ks<2; ++ks){
      short8 bh[2], bl[2];
#pragma unroll
      for (int pk=0; pk<2; ++pk){
        const int ch0 = ks*32 + q*8;
        const int pxl = 32*wid + 16*pk + lr;
        const int pxs = pxl ^ ((q&1)<<4);          // matches stage swizzle
        const float* rp = bp + ch0*TPX + pxs;
        float f[8];
#pragma unroll
        for (int j=0;j<8;++j) f[j] = rp[j*TPX];
        const float4 v0 = {f[0],f[1],f[2],f[3]};
        const float4 v1 = {f[4],f[5],f[6],f[7]};
        split8(v0, v1, bh[pk], bl[pk], dummy);
      }
#pragma unroll
      for (int cb=0; cb<4; ++cb)
#pragma unroll
        for (int pk=0; pk<2; ++pk){
          acc[cb][pk] = __builtin_amdgcn_mfma_f32_16x16x32_bf16(ah[cb][ks], bh[pk], acc[cb][pk], 0,0,0);
          acc[cb][pk] = __builtin_amdgcn_mfma_f32_16x16x32_bf16(ah[cb][ks], bl[pk], acc[cb][pk], 0,0,0);
          acc[cb][pk] = __builtin_amdgcn_mfma_f32_16x16x32_bf16(al[cb][ks], bh[pk], acc[cb][pk], 0,0,0);
        }
    }

    // stores (enter vmcnt queue; accounted in the counted waits above)
    {
      const unsigned mbase = (unsigned)(blockIdx.x*TPB + tl) * TPX;
#pragma unroll
      for (int pk=0; pk<2; ++pk){
        const unsigned P  = mbase + 32*wid + 16*pk + lr;
        const unsigned b2 = P / HW;
        const unsigned hw2 = P - b2*HW;
        float* ob = out + (size_t)b2*(CH*HW) + hw2 + (size_t)(4*q)*HW;
#pragma unroll
        for (int cb=0; cb<4; ++cb)
#pragma unroll
          for (int r=0; r<4; ++r)
            ob[(size_t)(16*cb + r)*HW] = acc[cb][pk][r] + ofsv[cb][r];
      }
    }
    asm volatile("s_barrier" ::: "memory");
    pb ^= 1;
  }
}

extern "C" void kernel_launch(void* const* d_in, const int* in_sizes, int n_in,
                              void* d_out, int out_size, void* d_ws, size_t ws_size,
                              hipStream_t stream){
  const float* X    = (const float*)d_in[0];
  const float* beta = (const float*)d_in[1];
  float* out = (float*)d_out;
  float* ws  = (float*)d_ws;
  float* SR  = ws;            // 4160 floats
  float* WM  = ws + 4160;     // 4096 (row-major, pre-scaled)
  float* OFS = WM + 4096;     // 64
  hipMemsetAsync(SR, 0, 4160*sizeof(float), stream);
  hipLaunchKernelGGL(k1_cov,   dim3(NBLK), dim3(256), 0, stream, X, SR);
  hipLaunchKernelGGL(k2_wm,    dim3(1),    dim3(256), 0, stream, SR, beta, WM, OFS);
  hipLaunchKernelGGL(k3_apply, dim3(NBLK), dim3(256), 0, stream, X, WM, OFS, out);
}

// Round 6
// 230.432 us; speedup vs baseline: 1.0388x; 1.0388x over previous
//
#include <hip/hip_runtime.h>

#define CH 64
#define HW 3136
#define MTOT 401408   // 128*3136
#define TPX 128       // px per k1 tile
#define K1_NBLK 784   // 784 blocks x 4 tiles x 128 px = 401408
#define K1_TPB 4

typedef __attribute__((ext_vector_type(8))) short short8;   // 8 bf16 (4 VGPRs)
typedef __attribute__((ext_vector_type(4))) float f32x4;
typedef __attribute__((ext_vector_type(4))) unsigned int u32x4;

// hi/lo bf16 split of 8 fp32 values (truncation + exact residual; proven r1-r5)
__device__ __forceinline__ void split8(const float4 a, const float4 b,
                                       short8& hi, short8& lo, float& ssum){
  const float f[8] = {a.x,a.y,a.z,a.w, b.x,b.y,b.z,b.w};
  u32x4 hp, lp;
#pragma unroll
  for (int j=0;j<4;++j){
    const unsigned int b0 = __float_as_uint(f[2*j]);
    const unsigned int b1 = __float_as_uint(f[2*j+1]);
    hp[j] = (b0 >> 16) | (b1 & 0xFFFF0000u);
    const float h0 = __uint_as_float(b0 & 0xFFFF0000u);
    const float h1 = __uint_as_float(b1 & 0xFFFF0000u);
    const unsigned int l0 = __float_as_uint(f[2*j]   - h0);
    const unsigned int l1 = __float_as_uint(f[2*j+1] - h1);
    lp[j] = (l0 >> 16) | (l1 & 0xFFFF0000u);
  }
  hi = __builtin_bit_cast(short8, hp);
  lo = __builtin_bit_cast(short8, lp);
  ssum += ((f[0]+f[1])+(f[2]+f[3])) + ((f[4]+f[5])+(f[6]+f[7]));
}

// ---------------- K1: covariance via split-bf16 MFMA, counted-vmcnt dbuf ----------------
__global__ __launch_bounds__(256) void k1_cov(const float* __restrict__ X,
                                              float* __restrict__ SR){
  constexpr int RG[10] = {0,1,1,2,2,2,3,3,3,3};
  constexpr int CG[10] = {0,0,1,0,1,2,0,1,2,3};
  __shared__ __align__(16) float buf[2][64*TPX];   // 2 x 32KB double buffer
  __shared__ float chs[64];

  const int t   = threadIdx.x;
  const int wid = __builtin_amdgcn_readfirstlane(t >> 6);
  const int l   = t & 63;
  const int lr  = l & 15;
  const int q   = l >> 4;

  f32x4 acc[10];
#pragma unroll
  for (int bi=0; bi<10; ++bi) acc[bi] = (f32x4){0.f,0.f,0.f,0.f};
  float sums[4] = {0.f,0.f,0.f,0.f};

  auto stage = [&](int tl, float* dst){
    const unsigned mbase = (unsigned)(blockIdx.x*K1_TPB + tl) * TPX;
#pragma unroll
    for (int j=0;j<8;++j){
      const int r  = 16*wid + 2*j + (l>>5);
      const int cb = (l&31) ^ (r&7);
      const unsigned m  = mbase + 4*cb;
      const unsigned b  = m / HW;
      const unsigned hw = m - b*HW;
      const float* src = X + (size_t)b*(CH*HW) + (size_t)r*HW + hw;
      __builtin_amdgcn_global_load_lds(
        (const __attribute__((address_space(1))) unsigned int*)src,
        (__attribute__((address_space(3))) unsigned int*)(dst + (16*wid + 2*j)*TPX),
        16, 0, 0);
    }
  };

  stage(0, buf[0]);
  int pb = 0;
#pragma unroll
  for (int tl=0; tl<K1_TPB; ++tl){
    if (tl+1 < K1_TPB){
      stage(tl+1, buf[pb^1]);
      asm volatile("s_waitcnt vmcnt(8)" ::: "memory");   // only tile tl's 8 loads done
    } else {
      asm volatile("s_waitcnt vmcnt(0)" ::: "memory");
    }
    __builtin_amdgcn_sched_barrier(0);
    asm volatile("s_barrier" ::: "memory");              // raw: no compiler vmcnt drain
    const char* bp = (const char*)buf[pb];
    short8 fh[4], fl[4];
#pragma unroll
    for (int g=0; g<4; ++g){
      const int r   = 16*g + lr;
      const int sw  = r & 7;
      const int cb0 = 8*wid + 2*q;
      const float4 v0 = *(const float4*)(bp + r*512 + 16*((cb0+0)^sw));
      const float4 v1 = *(const float4*)(bp + r*512 + 16*((cb0+1)^sw));
      split8(v0, v1, fh[g], fl[g], sums[g]);
    }
#pragma unroll
    for (int bi=0; bi<10; ++bi){
      acc[bi] = __builtin_amdgcn_mfma_f32_16x16x32_bf16(fh[RG[bi]], fh[CG[bi]], acc[bi], 0,0,0);
      acc[bi] = __builtin_amdgcn_mfma_f32_16x16x32_bf16(fh[RG[bi]], fl[CG[bi]], acc[bi], 0,0,0);
      acc[bi] = __builtin_amdgcn_mfma_f32_16x16x32_bf16(fl[RG[bi]], fh[CG[bi]], acc[bi], 0,0,0);
    }
    asm volatile("s_barrier" ::: "memory");              // all waves done reading buf[pb]
    pb ^= 1;
  }

#pragma unroll
  for (int g=0; g<4; ++g){
    sums[g] += __shfl_xor(sums[g], 16);
    sums[g] += __shfl_xor(sums[g], 32);
  }

  // deterministic cross-wave reduction (red aliases buf[0]; last-read tile was buf[1])
  float* red = &buf[0][0];
  for (int w=0; w<4; ++w){
    if (wid == w){
#pragma unroll
      for (int bi=0; bi<10; ++bi){
        const int row0 = RG[bi]*16 + 4*q;
        const int col  = CG[bi]*16 + lr;
#pragma unroll
        for (int r=0; r<4; ++r){
          float* d = &red[(row0+r)*64 + col];
          if (w==0) *d = acc[bi][r]; else *d += acc[bi][r];
        }
      }
      if (l < 16){
#pragma unroll
        for (int g=0; g<4; ++g){
          if (w==0) chs[g*16+l] = sums[g]; else chs[g*16+l] += sums[g];
        }
      }
    }
    __syncthreads();
  }

#pragma unroll
  for (int bi=0; bi<10; ++bi){
    const int r = RG[bi]*16 + (t>>4);
    const int c = CG[bi]*16 + (t&15);
    unsafeAtomicAdd(&SR[r*64+c], red[r*64+c]);
  }
  if (t < 64) unsafeAtomicAdd(&SR[4096+t], chs[t]);
}

// ---------------- K2: whitening matrix (unchanged) ----------------
__device__ __forceinline__ void mm_AtB(const float* a, const float* b, float* out,
                                       float alpha, const float* aff, float beta_){
  const int t = threadIdx.x;
  const int c2 = 2*(t & 31);
  const int r0 = 8*(t >> 5);
  float acc[8][2];
#pragma unroll
  for (int i=0;i<8;++i){ acc[i][0]=0.f; acc[i][1]=0.f; }
  for (int k=0;k<64;++k){
    const float2 bv = *(const float2*)&b[k*64 + c2];
    const float4 a0 = *(const float4*)&a[k*64 + r0];
    const float4 a1 = *(const float4*)&a[k*64 + r0 + 4];
    const float av[8] = {a0.x,a0.y,a0.z,a0.w, a1.x,a1.y,a1.z,a1.w};
#pragma unroll
    for (int i=0;i<8;++i){ acc[i][0] += av[i]*bv.x; acc[i][1] += av[i]*bv.y; }
  }
  float res[8][2];
#pragma unroll
  for (int i=0;i<8;++i){
    float f0 = alpha*acc[i][0], f1 = alpha*acc[i][1];
    if (aff){ f0 += beta_*aff[(r0+i)*64 + c2]; f1 += beta_*aff[(r0+i)*64 + c2 + 1]; }
    res[i][0]=f0; res[i][1]=f1;
  }
  __syncthreads();
#pragma unroll
  for (int i=0;i<8;++i){
    float2 o2; o2.x = res[i][0]; o2.y = res[i][1];
    *(float2*)&out[(r0+i)*64 + c2] = o2;
  }
  __syncthreads();
}

__global__ __launch_bounds__(256) void k2_wm(const float* __restrict__ SR,
                                             const float* __restrict__ beta,
                                             float* __restrict__ WM,
                                             float* __restrict__ OFS){
  __shared__ __align__(16) float bufE[4096];
  __shared__ __align__(16) float bufA[4096];
  __shared__ __align__(16) float bufB[4096];
  __shared__ float meanv[64];
  __shared__ float scal[2];
  const int t = threadIdx.x;
  const float inv_m = 1.f/(float)MTOT;
  if (t < 64) meanv[t] = SR[4096 + t]*inv_m;
  __syncthreads();
  for (int idx=t; idx<4096; idx+=256){
    const int r = idx >> 6, c = idx & 63;
    const int src = ((r >> 4) >= (c >> 4)) ? idx : (c*64 + r);
    const float cov = SR[src]*inv_m - meanv[r]*meanv[c];
    bufE[idx] = (r==c) ? (cov + 1e-5f - 1.f) : 0.9f*cov;
  }
  __syncthreads();
  float n2 = 0.f, tr = 0.f;
  for (int idx=t; idx<4096; idx+=256){
    const float e = bufE[idx];
    n2 += e*e;
    if ((idx >> 6) == (idx & 63)) tr += e;
  }
  bufA[t] = n2; bufB[t] = tr;
  __syncthreads();
  if (t < 64){
    bufA[t] = bufA[t]+bufA[t+64]+bufA[t+128]+bufA[t+192];
    bufB[t] = bufB[t]+bufB[t+64]+bufB[t+128]+bufB[t+192];
  }
  __syncthreads();
  if (t == 0){
    float s1=0.f, s2=0.f;
    for (int i=0;i<64;++i){ s1 += bufA[i]; s2 += bufB[i]; }
    scal[0] = s1; scal[1] = s2;
  }
  __syncthreads();
  const float frob2 = scal[0];
  const float trE   = scal[1];
  float wscale = 1.f;
  const float* wmLds;
  if (frob2 < 0.04f){
    mm_AtB(bufE, bufE, bufA, 1.f, nullptr, 0.f);   // E^2
    mm_AtB(bufA, bufE, bufB, 1.f, nullptr, 0.f);   // E^3
    for (int idx=t; idx<4096; idx+=256){
      const int r = idx >> 6, c = idx & 63;
      bufB[idx] = ((r==c)?1.f:0.f) - 0.5f*bufE[idx] + 0.375f*bufA[idx] - 0.3125f*bufB[idx];
    }
    mm_AtB(bufA, bufA, bufE, 1.f, nullptr, 0.f);   // E^4
    for (int idx=t; idx<4096; idx+=256)
      bufB[idx] += 0.2734375f*bufE[idx];           // 35/128
    wmLds = bufB;
  } else {
    const float rTr = 1.f/(trE + 64.f);
    for (int idx=t; idx<4096; idx+=256){
      const int r = idx >> 6, c = idx & 63;
      bufE[idx] = (bufE[idx] + ((r==c)?1.f:0.f))*rTr;
      bufA[idx] = (r==c)?1.f:0.f;
    }
    __syncthreads();
    for (int it=0; it<10; ++it){
      mm_AtB(bufA, bufE, bufB, 1.f, nullptr, 0.f);
      mm_AtB(bufA, bufB, bufB, 1.f, nullptr, 0.f);
      mm_AtB(bufA, bufB, bufA, -0.5f, bufA, 1.5f);
    }
    wscale = sqrtf(rTr);
    wmLds = bufA;
  }
  __syncthreads();
  // row-major scaled WM (k3 reads WM[c][k] contiguous in k)
  for (int idx=t; idx<4096; idx+=256) WM[idx] = wmLds[idx]*wscale;
  if (t < 64){
    float d = 0.f;
    for (int j=0;j<64;++j) d += wmLds[t*64 + j]*meanv[j];
    OFS[t] = beta[t] - d*wscale;
  }
}

// ---------------- K3: apply whitening via split-bf16 MFMA, no LDS (r4 best) ----------------
// out[c][p] = sum_k WM[c][k]*X[k][p] + OFS[c]; 3136 blocks x 128px.
// A = WM (stationary frags), B = X loaded direct from global (4x64B segs/instr).
__global__ __launch_bounds__(256) void k3_apply(const float* __restrict__ X,
                                                const float* __restrict__ WM,
                                                const float* __restrict__ OFS,
                                                float* __restrict__ out){
  const int t   = threadIdx.x;
  const int wid = __builtin_amdgcn_readfirstlane(t >> 6);
  const int l   = t & 63;
  const int lr  = l & 15;     // A-row / B-col / D-col lane index
  const int q   = l >> 4;     // k-octet

  // stationary WM A-fragments: row c = 16cb+lr, k = ks*32 + q*8 + j
  short8 ah[4][2], al[4][2];
  float dummy = 0.f;
#pragma unroll
  for (int cb=0; cb<4; ++cb)
#pragma unroll
    for (int ks=0; ks<2; ++ks){
      const float* wp = WM + (16*cb + lr)*64 + ks*32 + q*8;
      const float4 w0 = *(const float4*)wp;
      const float4 w1 = *(const float4*)(wp + 4);
      split8(w0, w1, ah[cb][ks], al[cb][ks], dummy);
    }

  // per-lane pixel (2 col-blocks of 16 px); per-lane b/hw -> straddle-safe
  unsigned bb[2], hwp[2];
#pragma unroll
  for (int pbk=0; pbk<2; ++pbk){
    const unsigned px = (unsigned)blockIdx.x*128u + 32u*wid + 16u*pbk + lr;
    bb[pbk]  = px / HW;
    hwp[pbk] = px - bb[pbk]*HW;
  }

  f32x4 acc[4][2];
#pragma unroll
  for (int cb=0; cb<4; ++cb)
#pragma unroll
    for (int pbk=0; pbk<2; ++pbk) acc[cb][pbk] = (f32x4){0.f,0.f,0.f,0.f};

#pragma unroll
  for (int ks=0; ks<2; ++ks){
    short8 bh[2], bl[2];
#pragma unroll
    for (int pbk=0; pbk<2; ++pbk){
      const float* xb = X + (size_t)bb[pbk]*(CH*HW) + hwp[pbk] + (size_t)(ks*32 + q*8)*HW;
      float f[8];
#pragma unroll
      for (int j=0;j<8;++j) f[j] = xb[(size_t)j*HW];
      const float4 v0 = {f[0],f[1],f[2],f[3]};
      const float4 v1 = {f[4],f[5],f[6],f[7]};
      split8(v0, v1, bh[pbk], bl[pbk], dummy);
    }
#pragma unroll
    for (int cb=0; cb<4; ++cb)
#pragma unroll
      for (int pbk=0; pbk<2; ++pbk){
        acc[cb][pbk] = __builtin_amdgcn_mfma_f32_16x16x32_bf16(ah[cb][ks], bh[pbk], acc[cb][pbk], 0,0,0);
        acc[cb][pbk] = __builtin_amdgcn_mfma_f32_16x16x32_bf16(ah[cb][ks], bl[pbk], acc[cb][pbk], 0,0,0);
        acc[cb][pbk] = __builtin_amdgcn_mfma_f32_16x16x32_bf16(al[cb][ks], bh[pbk], acc[cb][pbk], 0,0,0);
      }
  }

  // store: D col = px(lr), row c = 16cb + 4q + r
#pragma unroll
  for (int cb=0; cb<4; ++cb){
    float ofs[4];
#pragma unroll
    for (int r=0;r<4;++r) ofs[r] = OFS[16*cb + 4*q + r];
#pragma unroll
    for (int pbk=0; pbk<2; ++pbk){
      float* ob = out + (size_t)bb[pbk]*(CH*HW) + hwp[pbk] + (size_t)(16*cb + 4*q)*HW;
#pragma unroll
      for (int r=0;r<4;++r)
        ob[(size_t)r*HW] = acc[cb][pbk][r] + ofs[r];
    }
  }
}

extern "C" void kernel_launch(void* const* d_in, const int* in_sizes, int n_in,
                              void* d_out, int out_size, void* d_ws, size_t ws_size,
                              hipStream_t stream){
  const float* X    = (const float*)d_in[0];
  const float* beta = (const float*)d_in[1];
  float* out = (float*)d_out;
  float* ws  = (float*)d_ws;
  float* SR  = ws;            // 4160 floats
  float* WM  = ws + 4160;     // 4096 (row-major, pre-scaled)
  float* OFS = WM + 4096;     // 64
  hipMemsetAsync(SR, 0, 4160*sizeof(float), stream);
  hipLaunchKernelGGL(k1_cov,   dim3(K1_NBLK), dim3(256), 0, stream, X, SR);
  hipLaunchKernelGGL(k2_wm,    dim3(1),       dim3(256), 0, stream, SR, beta, WM, OFS);
  hipLaunchKernelGGL(k3_apply, dim3(3136),    dim3(256), 0, stream, X, WM, OFS, out);
}

// Round 7
// 228.608 us; speedup vs baseline: 1.0471x; 1.0080x over previous
//
#include <hip/hip_runtime.h>

#define CH 64
#define HW 3136
#define MTOT 401408   // 128*3136
#define TPX 128       // px per tile

typedef __attribute__((ext_vector_type(8))) short short8;   // 8 bf16 (4 VGPRs)
typedef __attribute__((ext_vector_type(4))) float f32x4;
typedef __attribute__((ext_vector_type(4))) unsigned int u32x4;

// hi/lo bf16 split of 8 fp32 values (truncation + exact residual; proven r1-r6)
__device__ __forceinline__ void split8(const float4 a, const float4 b,
                                       short8& hi, short8& lo, float& ssum){
  const float f[8] = {a.x,a.y,a.z,a.w, b.x,b.y,b.z,b.w};
  u32x4 hp, lp;
#pragma unroll
  for (int j=0;j<4;++j){
    const unsigned int b0 = __float_as_uint(f[2*j]);
    const unsigned int b1 = __float_as_uint(f[2*j+1]);
    hp[j] = (b0 >> 16) | (b1 & 0xFFFF0000u);
    const float h0 = __uint_as_float(b0 & 0xFFFF0000u);
    const float h1 = __uint_as_float(b1 & 0xFFFF0000u);
    const unsigned int l0 = __float_as_uint(f[2*j]   - h0);
    const unsigned int l1 = __float_as_uint(f[2*j+1] - h1);
    lp[j] = (l0 >> 16) | (l1 & 0xFFFF0000u);
  }
  hi = __builtin_bit_cast(short8, hp);
  lo = __builtin_bit_cast(short8, lp);
  ssum += ((f[0]+f[1])+(f[2]+f[3])) + ((f[4]+f[5])+(f[6]+f[7]));
}

// ---------------- K1: covariance via split-bf16 MFMA, dbuf, 512-block grid ----------------
// 512 blocks = exactly 2/CU resident (64KB LDS) -> zero dispatch tail.
// Blocks 0..63 process 7 tiles, 64..511 process 6: 64*7+448*6 = 3136 tiles.
__global__ __launch_bounds__(256) void k1_cov(const float* __restrict__ X,
                                              float* __restrict__ SR){
  constexpr int RG[10] = {0,1,1,2,2,2,3,3,3,3};
  constexpr int CG[10] = {0,0,1,0,1,2,0,1,2,3};
  __shared__ __align__(16) float buf[2][64*TPX];   // 2 x 32KB double buffer
  __shared__ float chs[64];

  const int t   = threadIdx.x;
  const int wid = __builtin_amdgcn_readfirstlane(t >> 6);
  const int l   = t & 63;
  const int lr  = l & 15;
  const int q   = l >> 4;
  const int bid = blockIdx.x;
  const int t0  = bid*6 + (bid < 64 ? bid : 64);   // global tile base
  const int nt  = (bid < 64) ? 7 : 6;

  f32x4 acc[10];
#pragma unroll
  for (int bi=0; bi<10; ++bi) acc[bi] = (f32x4){0.f,0.f,0.f,0.f};
  float sums[4] = {0.f,0.f,0.f,0.f};

  auto stage = [&](int tg, float* dst){
    const unsigned mbase = (unsigned)tg * TPX;
#pragma unroll
    for (int j=0;j<8;++j){
      const int r  = 16*wid + 2*j + (l>>5);
      const int cb = (l&31) ^ (r&7);
      const unsigned m  = mbase + 4*cb;
      const unsigned b  = m / HW;
      const unsigned hw = m - b*HW;
      const float* src = X + (size_t)b*(CH*HW) + (size_t)r*HW + hw;
      __builtin_amdgcn_global_load_lds(
        (const __attribute__((address_space(1))) unsigned int*)src,
        (__attribute__((address_space(3))) unsigned int*)(dst + (16*wid + 2*j)*TPX),
        16, 0, 0);
    }
  };

  stage(t0, buf[0]);
  int pb = 0;
  for (int tl=0; tl<nt; ++tl){
    if (tl+1 < nt){
      stage(t0+tl+1, buf[pb^1]);
      asm volatile("s_waitcnt vmcnt(8)" ::: "memory");   // only tile tl's 8 loads done
    } else {
      asm volatile("s_waitcnt vmcnt(0)" ::: "memory");
    }
    __builtin_amdgcn_sched_barrier(0);
    asm volatile("s_barrier" ::: "memory");
    const char* bp = (const char*)buf[pb];
    short8 fh[4], fl[4];
#pragma unroll
    for (int g=0; g<4; ++g){
      const int r   = 16*g + lr;
      const int sw  = r & 7;
      const int cb0 = 8*wid + 2*q;
      const float4 v0 = *(const float4*)(bp + r*512 + 16*((cb0+0)^sw));
      const float4 v1 = *(const float4*)(bp + r*512 + 16*((cb0+1)^sw));
      split8(v0, v1, fh[g], fl[g], sums[g]);
    }
#pragma unroll
    for (int bi=0; bi<10; ++bi){
      acc[bi] = __builtin_amdgcn_mfma_f32_16x16x32_bf16(fh[RG[bi]], fh[CG[bi]], acc[bi], 0,0,0);
      acc[bi] = __builtin_amdgcn_mfma_f32_16x16x32_bf16(fh[RG[bi]], fl[CG[bi]], acc[bi], 0,0,0);
      acc[bi] = __builtin_amdgcn_mfma_f32_16x16x32_bf16(fl[RG[bi]], fh[CG[bi]], acc[bi], 0,0,0);
    }
    asm volatile("s_barrier" ::: "memory");
    pb ^= 1;
  }

#pragma unroll
  for (int g=0; g<4; ++g){
    sums[g] += __shfl_xor(sums[g], 16);
    sums[g] += __shfl_xor(sums[g], 32);
  }

  // deterministic cross-wave reduction (red aliases buf[0])
  float* red = &buf[0][0];
  for (int w=0; w<4; ++w){
    if (wid == w){
#pragma unroll
      for (int bi=0; bi<10; ++bi){
        const int row0 = RG[bi]*16 + 4*q;
        const int col  = CG[bi]*16 + lr;
#pragma unroll
        for (int r=0; r<4; ++r){
          float* d = &red[(row0+r)*64 + col];
          if (w==0) *d = acc[bi][r]; else *d += acc[bi][r];
        }
      }
      if (l < 16){
#pragma unroll
        for (int g=0; g<4; ++g){
          if (w==0) chs[g*16+l] = sums[g]; else chs[g*16+l] += sums[g];
        }
      }
    }
    __syncthreads();
  }

#pragma unroll
  for (int bi=0; bi<10; ++bi){
    const int r = RG[bi]*16 + (t>>4);
    const int c = CG[bi]*16 + (t&15);
    unsafeAtomicAdd(&SR[r*64+c], red[r*64+c]);
  }
  if (t < 64) unsafeAtomicAdd(&SR[4096+t], chs[t]);
}

// ---------------- K2: whitening matrix (unchanged) ----------------
__device__ __forceinline__ void mm_AtB(const float* a, const float* b, float* out,
                                       float alpha, const float* aff, float beta_){
  const int t = threadIdx.x;
  const int c2 = 2*(t & 31);
  const int r0 = 8*(t >> 5);
  float acc[8][2];
#pragma unroll
  for (int i=0;i<8;++i){ acc[i][0]=0.f; acc[i][1]=0.f; }
  for (int k=0;k<64;++k){
    const float2 bv = *(const float2*)&b[k*64 + c2];
    const float4 a0 = *(const float4*)&a[k*64 + r0];
    const float4 a1 = *(const float4*)&a[k*64 + r0 + 4];
    const float av[8] = {a0.x,a0.y,a0.z,a0.w, a1.x,a1.y,a1.z,a1.w};
#pragma unroll
    for (int i=0;i<8;++i){ acc[i][0] += av[i]*bv.x; acc[i][1] += av[i]*bv.y; }
  }
  float res[8][2];
#pragma unroll
  for (int i=0;i<8;++i){
    float f0 = alpha*acc[i][0], f1 = alpha*acc[i][1];
    if (aff){ f0 += beta_*aff[(r0+i)*64 + c2]; f1 += beta_*aff[(r0+i)*64 + c2 + 1]; }
    res[i][0]=f0; res[i][1]=f1;
  }
  __syncthreads();
#pragma unroll
  for (int i=0;i<8;++i){
    float2 o2; o2.x = res[i][0]; o2.y = res[i][1];
    *(float2*)&out[(r0+i)*64 + c2] = o2;
  }
  __syncthreads();
}

__global__ __launch_bounds__(256) void k2_wm(const float* __restrict__ SR,
                                             const float* __restrict__ beta,
                                             float* __restrict__ WM,
                                             float* __restrict__ OFS){
  __shared__ __align__(16) float bufE[4096];
  __shared__ __align__(16) float bufA[4096];
  __shared__ __align__(16) float bufB[4096];
  __shared__ float meanv[64];
  __shared__ float scal[2];
  const int t = threadIdx.x;
  const float inv_m = 1.f/(float)MTOT;
  if (t < 64) meanv[t] = SR[4096 + t]*inv_m;
  __syncthreads();
  for (int idx=t; idx<4096; idx+=256){
    const int r = idx >> 6, c = idx & 63;
    const int src = ((r >> 4) >= (c >> 4)) ? idx : (c*64 + r);
    const float cov = SR[src]*inv_m - meanv[r]*meanv[c];
    bufE[idx] = (r==c) ? (cov + 1e-5f - 1.f) : 0.9f*cov;
  }
  __syncthreads();
  float n2 = 0.f, tr = 0.f;
  for (int idx=t; idx<4096; idx+=256){
    const float e = bufE[idx];
    n2 += e*e;
    if ((idx >> 6) == (idx & 63)) tr += e;
  }
  bufA[t] = n2; bufB[t] = tr;
  __syncthreads();
  if (t < 64){
    bufA[t] = bufA[t]+bufA[t+64]+bufA[t+128]+bufA[t+192];
    bufB[t] = bufB[t]+bufB[t+64]+bufB[t+128]+bufB[t+192];
  }
  __syncthreads();
  if (t == 0){
    float s1=0.f, s2=0.f;
    for (int i=0;i<64;++i){ s1 += bufA[i]; s2 += bufB[i]; }
    scal[0] = s1; scal[1] = s2;
  }
  __syncthreads();
  const float frob2 = scal[0];
  const float trE   = scal[1];
  float wscale = 1.f;
  const float* wmLds;
  if (frob2 < 0.04f){
    mm_AtB(bufE, bufE, bufA, 1.f, nullptr, 0.f);   // E^2
    mm_AtB(bufA, bufE, bufB, 1.f, nullptr, 0.f);   // E^3
    for (int idx=t; idx<4096; idx+=256){
      const int r = idx >> 6, c = idx & 63;
      bufB[idx] = ((r==c)?1.f:0.f) - 0.5f*bufE[idx] + 0.375f*bufA[idx] - 0.3125f*bufB[idx];
    }
    mm_AtB(bufA, bufA, bufE, 1.f, nullptr, 0.f);   // E^4
    for (int idx=t; idx<4096; idx+=256)
      bufB[idx] += 0.2734375f*bufE[idx];           // 35/128
    wmLds = bufB;
  } else {
    const float rTr = 1.f/(trE + 64.f);
    for (int idx=t; idx<4096; idx+=256){
      const int r = idx >> 6, c = idx & 63;
      bufE[idx] = (bufE[idx] + ((r==c)?1.f:0.f))*rTr;
      bufA[idx] = (r==c)?1.f:0.f;
    }
    __syncthreads();
    for (int it=0; it<10; ++it){
      mm_AtB(bufA, bufE, bufB, 1.f, nullptr, 0.f);
      mm_AtB(bufA, bufB, bufB, 1.f, nullptr, 0.f);
      mm_AtB(bufA, bufB, bufA, -0.5f, bufA, 1.5f);
    }
    wscale = sqrtf(rTr);
    wmLds = bufA;
  }
  __syncthreads();
  for (int idx=t; idx<4096; idx+=256) WM[idx] = wmLds[idx]*wscale;
  if (t < 64){
    float d = 0.f;
    for (int j=0;j<64;++j) d += wmLds[t*64 + j]*meanv[j];
    OFS[t] = beta[t] - d*wscale;
  }
}

// ---------------- K3: MFMA apply, coalesced in (gload_lds) AND out (LDS transpose) ----------------
// 3136 blocks x 128px. One 32KB LDS tile reused input->output.
// Input swizzle (r5-verified): px-bit4 ^ ch-bit3. Output swizzle: px-bit4 ^ ch-bit2.
__global__ __launch_bounds__(256) void k3_apply(const float* __restrict__ X,
                                                const float* __restrict__ WM,
                                                const float* __restrict__ OFS,
                                                float* __restrict__ out){
  __shared__ __align__(16) float tile[64*TPX];   // 32KB
  const int t   = threadIdx.x;
  const int wid = __builtin_amdgcn_readfirstlane(t >> 6);
  const int l   = t & 63;
  const int lr  = l & 15;     // A-row / B-col(px) / D-col
  const int q   = l >> 4;     // k-octet

  // ---- stage input tile (coalesced 512B rows; inverse-swizzled source) ----
  {
    const unsigned mbase = (unsigned)blockIdx.x * TPX;
#pragma unroll
    for (int j=0;j<8;++j){
      const int r = 16*wid + 2*j + (l>>5);
      const unsigned pxs = 4*(l&31);
      const unsigned m  = mbase + (pxs ^ (((r>>3)&1u)<<4));
      const unsigned b  = m / HW;
      const unsigned hw = m - b*HW;
      const float* src = X + (size_t)b*(CH*HW) + (size_t)r*HW + hw;
      __builtin_amdgcn_global_load_lds(
        (const __attribute__((address_space(1))) unsigned int*)src,
        (__attribute__((address_space(3))) unsigned int*)(tile + (16*wid + 2*j)*TPX),
        16, 0, 0);
    }
  }

  // ---- A-frags from WM while the stage flies (row c = 16cb+lr, k = ks*32+q*8+j) ----
  short8 ah[4][2], al[4][2];
  float dummy = 0.f;
#pragma unroll
  for (int cb=0; cb<4; ++cb)
#pragma unroll
    for (int ks=0; ks<2; ++ks){
      const float* wp = WM + (16*cb + lr)*64 + ks*32 + q*8;
      const float4 w0 = *(const float4*)wp;
      const float4 w1 = *(const float4*)(wp + 4);
      split8(w0, w1, ah[cb][ks], al[cb][ks], dummy);
    }

  asm volatile("s_waitcnt vmcnt(0)" ::: "memory");
  __syncthreads();

  // ---- B-frags from LDS (2-way conflict = free) + MFMA ----
  f32x4 acc[4][2];
#pragma unroll
  for (int cb=0; cb<4; ++cb)
#pragma unroll
    for (int pk=0; pk<2; ++pk) acc[cb][pk] = (f32x4){0.f,0.f,0.f,0.f};

#pragma unroll
  for (int ks=0; ks<2; ++ks){
    short8 bh[2], bl[2];
#pragma unroll
    for (int pk=0; pk<2; ++pk){
      const int ch0 = ks*32 + q*8;
      const int pxl = 32*wid + 16*pk + lr;
      const int pxs = pxl ^ ((q&1)<<4);           // matches stage swizzle
      const float* rp = tile + ch0*TPX + pxs;
      float f[8];
#pragma unroll
      for (int j=0;j<8;++j) f[j] = rp[j*TPX];
      const float4 v0 = {f[0],f[1],f[2],f[3]};
      const float4 v1 = {f[4],f[5],f[6],f[7]};
      split8(v0, v1, bh[pk], bl[pk], dummy);
    }
#pragma unroll
    for (int cb=0; cb<4; ++cb)
#pragma unroll
      for (int pk=0; pk<2; ++pk){
        acc[cb][pk] = __builtin_amdgcn_mfma_f32_16x16x32_bf16(ah[cb][ks], bh[pk], acc[cb][pk], 0,0,0);
        acc[cb][pk] = __builtin_amdgcn_mfma_f32_16x16x32_bf16(ah[cb][ks], bl[pk], acc[cb][pk], 0,0,0);
        acc[cb][pk] = __builtin_amdgcn_mfma_f32_16x16x32_bf16(al[cb][ks], bh[pk], acc[cb][pk], 0,0,0);
      }
  }
  __syncthreads();   // all waves done reading input tile

  // ---- acc -> LDS transpose (ch-bit2 XOR on px-bit4 -> 2-way conflicts, free) ----
#pragma unroll
  for (int cb=0; cb<4; ++cb)
#pragma unroll
    for (int pk=0; pk<2; ++pk)
#pragma unroll
      for (int r=0; r<4; ++r){
        const int ch = 16*cb + 4*q + r;
        const int px = (32*wid + 16*pk + lr) ^ (((ch>>2)&1)<<4);
        tile[ch*TPX + px] = acc[cb][pk][r];
      }
  __syncthreads();

  // ---- coalesced stores: lane l owns px {2l,2l+1}, 512B per instr (r2-proven pattern) ----
  {
    const int c0 = 16*wid;
    const unsigned P2 = (unsigned)blockIdx.x*TPX + 2*l;
    const unsigned b2 = P2 / HW;
    const unsigned hw2 = P2 - b2*HW;
    float* ob = out + (size_t)b2*(CH*HW) + hw2;
#pragma unroll
    for (int i=0;i<16;++i){
      const int c = c0 + i;
      const int px = (2*l) ^ (((c>>2)&1)<<4);
      const float2 v = *(const float2*)&tile[c*TPX + px];
      const float o = OFS[c];
      float2 pkv; pkv.x = v.x + o; pkv.y = v.y + o;
      *(float2*)(ob + (size_t)c*HW) = pkv;
    }
  }
}

extern "C" void kernel_launch(void* const* d_in, const int* in_sizes, int n_in,
                              void* d_out, int out_size, void* d_ws, size_t ws_size,
                              hipStream_t stream){
  const float* X    = (const float*)d_in[0];
  const float* beta = (const float*)d_in[1];
  float* out = (float*)d_out;
  float* ws  = (float*)d_ws;
  float* SR  = ws;            // 4160 floats
  float* WM  = ws + 4160;     // 4096 (row-major, pre-scaled)
  float* OFS = WM + 4096;     // 64
  hipMemsetAsync(SR, 0, 4160*sizeof(float), stream);
  hipLaunchKernelGGL(k1_cov,   dim3(512),  dim3(256), 0, stream, X, SR);
  hipLaunchKernelGGL(k2_wm,    dim3(1),    dim3(256), 0, stream, SR, beta, WM, OFS);
  hipLaunchKernelGGL(k3_apply, dim3(3136), dim3(256), 0, stream, X, WM, OFS, out);
}